// Round 1
// baseline (114.753 us; speedup 1.0000x reference)
//
#include <hip/hip_runtime.h>
#include <hip/hip_bf16.h>

#define BB 16
#define NQ 64
#define NK 512
#define HD 256   // H = QS = KS = VD = 256

typedef __attribute__((ext_vector_type(8))) short short8;
typedef __attribute__((ext_vector_type(4))) float f32x4;

__device__ __forceinline__ ushort bf16_rne(float v) {
    unsigned u = __float_as_uint(v);
    return (ushort)((u + 0x7FFFu + ((u >> 16) & 1u)) >> 16);
}
__device__ __forceinline__ float bf16_to_f(ushort h) {
    return __uint_as_float(((unsigned)h) << 16);
}

// ---------------------------------------------------------------------------
// W-only conversion (tiny): W fp32 [k][n] -> hi/lo bf16 TRANSPOSED [n][k].
// 128 blocks.  Scattered L2 reads, coalesced ushort4 writes.
// ---------------------------------------------------------------------------
__global__ __launch_bounds__(256) void wconv(
    const float* __restrict__ wq, const float* __restrict__ wk,
    ushort* __restrict__ wqh, ushort* __restrict__ wql,
    ushort* __restrict__ wkh, ushort* __restrict__ wkl)
{
    int widx = blockIdx.x * 256 + threadIdx.x;     // 0..32767
    const float* W; ushort *wh, *wl;
    if (widx < 16384) { W = wq; wh = wqh; wl = wql; }
    else { W = wk; wh = wkh; wl = wkl; widx -= 16384; }
    int n  = widx >> 6;
    int k4 = (widx & 63) * 4;
    ushort hh[4], ll[4];
    #pragma unroll
    for (int c = 0; c < 4; ++c) {
        float v = W[(k4 + c) * 256 + n];
        hh[c] = bf16_rne(v);
        ll[c] = bf16_rne(v - bf16_to_f(hh[c]));
    }
    *(ushort4*)&wh[n * 256 + k4] = make_ushort4(hh[0], hh[1], hh[2], hh[3]);
    *(ushort4*)&wl[n * 256 + k4] = make_ushort4(ll[0], ll[1], ll[2], ll[3]);
}

// ---------------------------------------------------------------------------
// Projection GEMM with FUSED A-conversion: A fp32 -> hi/lo bf16 in registers
// -> XOR-swizzled LDS; W^T pre-converted (wconv).  C = AhWh + AlWh + AhWl,
// epilogue: exp2(acc*scale)  (score kernel consumes e^{2q}, e^{2k} directly).
// Tile 64x64, BK=64, 576 blocks (144 x 4), 4 waves.
// ---------------------------------------------------------------------------
__global__ __launch_bounds__(256, 2) void proj_fused(
    const float* __restrict__ queries, const float* __restrict__ keys,
    const ushort* __restrict__ wqh, const ushort* __restrict__ wql,
    const ushort* __restrict__ wkh, const ushort* __restrict__ wkl,
    float* __restrict__ qp, float* __restrict__ kp, float scale)
{
    __shared__ ushort AsH[64 * 64], AsL[64 * 64];
    __shared__ ushort BsH[64 * 64], BsL[64 * 64];

    const float* A; const ushort *Bh, *Bl; float* C; int rows0;
    const int bx = blockIdx.x;
    if (bx < 16) { A = queries; Bh = wqh; Bl = wql; C = qp; rows0 = bx * 64; }
    else         { A = keys;    Bh = wkh; Bl = wkl; C = kp; rows0 = (bx - 16) * 64; }
    const int cols0 = blockIdx.y * 64;

    const int t = threadIdx.x, lane = t & 63, wave = t >> 6;
    const int quad = lane >> 4, l15 = lane & 15;
    const int sr  = t >> 2;          // staging row / n: 0..63
    const int sc2 = (t & 3) * 2;     // chunk pair base: 0,2,4,6

    f32x4 acc[4];
    #pragma unroll
    for (int j = 0; j < 4; ++j) acc[j] = (f32x4){0.f, 0.f, 0.f, 0.f};

    for (int k0 = 0; k0 < 256; k0 += 64) {
        // global loads: A fp32 (16 elems), W^T bf16 hi/lo (2 chunks each)
        const float* arow = &A[(size_t)(rows0 + sr) * 256 + k0 + sc2 * 8];
        float4 a0 = *(const float4*)&arow[0];
        float4 a1 = *(const float4*)&arow[4];
        float4 a2 = *(const float4*)&arow[8];
        float4 a3 = *(const float4*)&arow[12];
        const ushort* bhp = &Bh[(size_t)(cols0 + sr) * 256 + k0 + sc2 * 8];
        const ushort* blp = &Bl[(size_t)(cols0 + sr) * 256 + k0 + sc2 * 8];
        short8 b0h = *(const short8*)&bhp[0];
        short8 b1h = *(const short8*)&bhp[8];
        short8 b0l = *(const short8*)&blp[0];
        short8 b1l = *(const short8*)&blp[8];

        __syncthreads();   // previous tile's compute done

        // convert A to hi/lo bf16, pack
        float av[16] = {a0.x, a0.y, a0.z, a0.w, a1.x, a1.y, a1.z, a1.w,
                        a2.x, a2.y, a2.z, a2.w, a3.x, a3.y, a3.z, a3.w};
        short8 ah0, ah1, al0, al1;
        #pragma unroll
        for (int e = 0; e < 8; ++e) {
            ushort h0 = bf16_rne(av[e]);
            ushort h1 = bf16_rne(av[8 + e]);
            ah0[e] = (short)h0;
            ah1[e] = (short)h1;
            al0[e] = (short)bf16_rne(av[e] - bf16_to_f(h0));
            al1[e] = (short)bf16_rne(av[8 + e] - bf16_to_f(h1));
        }
        // XOR-swizzled LDS stores (chunk slot = c ^ (row&7))
        {
            int s0 = sr * 8 + ((sc2 + 0) ^ (sr & 7));
            int s1 = sr * 8 + ((sc2 + 1) ^ (sr & 7));
            *(short8*)&AsH[s0 * 8] = ah0;
            *(short8*)&AsH[s1 * 8] = ah1;
            *(short8*)&AsL[s0 * 8] = al0;
            *(short8*)&AsL[s1 * 8] = al1;
            *(short8*)&BsH[s0 * 8] = b0h;
            *(short8*)&BsH[s1 * 8] = b1h;
            *(short8*)&BsL[s0 * 8] = b0l;
            *(short8*)&BsL[s1 * 8] = b1l;
        }
        __syncthreads();

        #pragma unroll
        for (int ks = 0; ks < 2; ++ks) {
            const int c = ks * 4 + quad;
            short8 aH, aL, bH[4], bL[4];
            {
                int r = wave * 16 + l15;
                int slot = r * 8 + (c ^ (r & 7));
                aH = *(const short8*)&AsH[slot * 8];
                aL = *(const short8*)&AsL[slot * 8];
            }
            #pragma unroll
            for (int ns = 0; ns < 4; ++ns) {
                int n = ns * 16 + l15;
                int slot = n * 8 + (c ^ (n & 7));
                bH[ns] = *(const short8*)&BsH[slot * 8];
                bL[ns] = *(const short8*)&BsL[slot * 8];
            }
            #pragma unroll
            for (int ns = 0; ns < 4; ++ns)
                acc[ns] = __builtin_amdgcn_mfma_f32_16x16x32_bf16(aH, bH[ns], acc[ns], 0, 0, 0);
            #pragma unroll
            for (int ns = 0; ns < 4; ++ns)
                acc[ns] = __builtin_amdgcn_mfma_f32_16x16x32_bf16(aL, bH[ns], acc[ns], 0, 0, 0);
            #pragma unroll
            for (int ns = 0; ns < 4; ++ns)
                acc[ns] = __builtin_amdgcn_mfma_f32_16x16x32_bf16(aH, bL[ns], acc[ns], 0, 0, 0);
        }
    }

    // epilogue: C/D col=lane&15, row=quad*4+reg.  Store exp2(x*scale) so the
    // score kernel consumes e^{2q}/e^{2k} directly (bit-identical to its old
    // in-kernel exp2, computed once instead of up to 8x).
    const int rbase = rows0 + wave * 16 + quad * 4;
    #pragma unroll
    for (int ns = 0; ns < 4; ++ns) {
        int col = cols0 + ns * 16 + l15;
        #pragma unroll
        for (int r = 0; r < 4; ++r)
            C[(size_t)(rbase + r) * 256 + col] =
                __builtin_amdgcn_exp2f(acc[ns][r] * scale);
    }
}

// ---------------------------------------------------------------------------
// Segment flash partial, qtile=8.  Block = (b, q-tile of 8, 64-key segment).
// qp/kp now hold EQ=e^{2q}, EK=e^{2k} (precomputed by proj epilogue).
// Inner loop uses a 4-way grouped reciprocal:
//   sum_i w_i/p_i = [d23*(w0*p1+w1*p0) + d01*(w2*p3+w3*p2)] / (d01*d23),
// p_i = 1 + EQ_i*EK_i >= 1  ->  1 rcp per 4 channels (was 4), no exp2.
// Per-j wave cost drops ~416 -> ~288 cycles (trans ops /4).
// Masked keys -> s=-1e6 set explicitly (unchanged).
// ---------------------------------------------------------------------------
__global__ __launch_bounds__(256) void score_pv_seg2(
    const float* __restrict__ qp,      // [B*NQ, H]  EQ = exp2(q * 2/ln2)
    const float* __restrict__ kp,      // [B*NK, H]  EK = exp2(k * 2/ln2)
    const float* __restrict__ values,  // [B, NK, VD]
    const int*   __restrict__ vlens,   // [B]
    const float* __restrict__ w_v,     // [H]
    float* __restrict__ pO,            // [B][8qt][8seg][8q][256]
    float* __restrict__ pM,            // [B][8qt][8seg][8q]
    float* __restrict__ pL)            // [B][8qt][8seg][8q]
{
    __shared__ float eq[8][260];
    __shared__ float wv[HD];
    __shared__ float Ps[8][66];
    __shared__ float part[4][8][260];

    const int b   = blockIdx.x & 15;
    const int qt  = blockIdx.x >> 4;    // 0..7
    const int seg = blockIdx.y;         // 0..7
    const int vl  = vlens[b];
    if (seg * 64 >= vl) return;

    const int t = threadIdx.x, lane = t & 63, wave = t >> 6;

    // stage EQ for 8 rows (plain copy — already exponentiated), and w
    const float* qsrc = qp + ((size_t)b * NQ + qt * 8) * HD;
    #pragma unroll
    for (int i = 0; i < 2; ++i) {
        int idx = i * 256 + t;           // 0..511 float4s
        int row = idx >> 6, c4 = (idx & 63) * 4;
        *(float4*)&eq[row][c4] = *(const float4*)&qsrc[(size_t)row * HD + c4];
    }
    if (t < 64) *(float4*)&wv[t * 4] = *(const float4*)&w_v[t * 4];
    __syncthreads();

    // Wsum
    float Wsum;
    {
        float ws = wv[lane] + wv[lane + 64] + wv[lane + 128] + wv[lane + 192];
        #pragma unroll
        for (int off = 32; off; off >>= 1) ws += __shfl_xor(ws, off);
        Wsum = ws;
    }

    // ---- scores: lane -> (key = wave*16 + lane>>2, ch = lane&3) ----
    const int key = wave * 16 + (lane >> 2);
    const int ch  = lane & 3;
    const int kg  = seg * 64 + key;
    const float* krow = kp + ((size_t)b * NK + kg) * HD + ch * 4;

    float s[8] = {0.f, 0.f, 0.f, 0.f, 0.f, 0.f, 0.f, 0.f};
    #pragma unroll
    for (int j = 0; j < 16; ++j) {
        const int h = j * 16 + ch * 4;
        float4 ek = *(const float4*)&krow[j * 16];   // EK, no exp2 needed
        float4 w4 = *(const float4*)&wv[h];
        #pragma unroll
        for (int qi = 0; qi < 8; ++qi) {
            float4 q4 = *(const float4*)&eq[qi][h];   // LDS broadcast (EQ)
            float p0 = fmaf(q4.x, ek.x, 1.f);
            float p1 = fmaf(q4.y, ek.y, 1.f);
            float p2 = fmaf(q4.z, ek.z, 1.f);
            float p3 = fmaf(q4.w, ek.w, 1.f);
            float d01 = p0 * p1;
            float d23 = p2 * p3;
            float n01 = fmaf(w4.x, p1, w4.y * p0);
            float n23 = fmaf(w4.z, p3, w4.w * p2);
            float num = fmaf(d01, n23, d23 * n01);
            float r   = __builtin_amdgcn_rcpf(d01 * d23);
            s[qi] = fmaf(num, r, s[qi]);
        }
    }
    #pragma unroll
    for (int qi = 0; qi < 8; ++qi) {
        s[qi] += __shfl_xor(s[qi], 1);
        s[qi] += __shfl_xor(s[qi], 2);
    }
    if (ch == 0) {
        const bool masked = (kg >= vl);
        #pragma unroll
        for (int qi = 0; qi < 8; ++qi)
            Ps[qi][key] = masked ? -1e6f : fmaf(-2.f, s[qi], Wsum);
    }
    __syncthreads();

    // ---- per-segment softmax: wave handles q rows wave*2, wave*2+1 ----
    const float L2E = 1.4426950408889634f;
    #pragma unroll
    for (int r = 0; r < 2; ++r) {
        const int row = wave * 2 + r;
        float sv = Ps[row][lane];
        float m = sv;
        #pragma unroll
        for (int off = 32; off; off >>= 1) m = fmaxf(m, __shfl_xor(m, off));
        float e = __builtin_amdgcn_exp2f((sv - m) * L2E);
        float l = e;
        #pragma unroll
        for (int off = 32; off; off >>= 1) l += __shfl_xor(l, off);
        Ps[row][lane] = e;
        if (lane == 0) {
            size_t mi = (((size_t)(b * 8 + qt) * 8 + seg)) * 8 + row;
            pM[mi] = m;
            pL[mi] = l;
        }
    }
    __syncthreads();

    // ---- PV: wave handles its 16 keys; lane owns vd = lane*4 ----
    f32x4 acc[8];
    #pragma unroll
    for (int qi = 0; qi < 8; ++qi) acc[qi] = (f32x4){0.f, 0.f, 0.f, 0.f};
    const float* vbase = values + ((size_t)b * NK + seg * 64 + wave * 16) * HD;
    #pragma unroll
    for (int i = 0; i < 16; ++i) {
        float4 v = *(const float4*)&vbase[(size_t)i * HD + lane * 4];
        #pragma unroll
        for (int qi = 0; qi < 8; ++qi) {
            float p = Ps[qi][wave * 16 + i];          // LDS broadcast
            acc[qi][0] = fmaf(p, v.x, acc[qi][0]);
            acc[qi][1] = fmaf(p, v.y, acc[qi][1]);
            acc[qi][2] = fmaf(p, v.z, acc[qi][2]);
            acc[qi][3] = fmaf(p, v.w, acc[qi][3]);
        }
    }
    #pragma unroll
    for (int qi = 0; qi < 8; ++qi)
        *(f32x4*)&part[wave][qi][lane * 4] = acc[qi];
    __syncthreads();

    // ---- cross-wave reduce + store partials ----
    const size_t ob = (((size_t)(b * 8 + qt) * 8 + seg)) * 8 * 256;
    #pragma unroll
    for (int i = 0; i < 2; ++i) {
        int idx = i * 256 + t;           // 0..511
        int qi = idx >> 6, c4 = (idx & 63) * 4;
        float4 p0 = *(const float4*)&part[0][qi][c4];
        float4 p1 = *(const float4*)&part[1][qi][c4];
        float4 p2 = *(const float4*)&part[2][qi][c4];
        float4 p3 = *(const float4*)&part[3][qi][c4];
        float4 o;
        o.x = (p0.x + p1.x) + (p2.x + p3.x);
        o.y = (p0.y + p1.y) + (p2.y + p3.y);
        o.z = (p0.z + p1.z) + (p2.z + p3.z);
        o.w = (p0.w + p1.w) + (p2.w + p3.w);
        *(float4*)&pO[ob + (size_t)qi * 256 + c4] = o;
    }
}

// ---------------------------------------------------------------------------
// Combine: block per (b,q), 256 threads (one vd element each).
// O = sum_i e2(m_i-m)*O_i / sum_i e2(m_i-m)*l_i, i < nc (<=8 segs).
// ---------------------------------------------------------------------------
__global__ __launch_bounds__(256) void combine_seg2(
    const float* __restrict__ pO, const float* __restrict__ pM,
    const float* __restrict__ pL, const int* __restrict__ vlens,
    float* __restrict__ out)
{
    const int b  = blockIdx.x >> 6;
    const int q  = blockIdx.x & 63;
    const int t  = threadIdx.x;
    const int vl = vlens[b];
    const int nc = (vl + 63) >> 6;
    const int qt = q >> 3, qi = q & 7;
    const float L2E = 1.4426950408889634f;

    const size_t base = (size_t)(b * 8 + qt) * 8;   // + seg, then *8 + qi

    float mi[8], li[8];
    float m = -3e38f;
    #pragma unroll
    for (int i = 0; i < 8; ++i) {
        if (i < nc) {
            mi[i] = pM[(base + i) * 8 + qi];
            li[i] = pL[(base + i) * 8 + qi];
            m = fmaxf(m, mi[i]);
        }
    }
    float L = 0.f, wi[8];
    #pragma unroll
    for (int i = 0; i < 8; ++i) {
        if (i < nc) {
            wi[i] = __builtin_amdgcn_exp2f((mi[i] - m) * L2E);
            L = fmaf(li[i], wi[i], L);
        }
    }
    float acc = 0.f;
    #pragma unroll
    for (int i = 0; i < 8; ++i) {
        if (i < nc) acc = fmaf(wi[i], pO[((base + i) * 8 + qi) * 256 + t], acc);
    }
    out[((size_t)(b * 64 + q)) * 256 + t] = acc * __builtin_amdgcn_rcpf(L);
}

extern "C" void kernel_launch(void* const* d_in, const int* in_sizes, int n_in,
                              void* d_out, int out_size, void* d_ws, size_t ws_size,
                              hipStream_t stream) {
    const float* queries = (const float*)d_in[0];
    const float* keys    = (const float*)d_in[1];
    const float* values  = (const float*)d_in[2];
    const int*   vlens   = (const int*)d_in[3];
    const float* W_q     = (const float*)d_in[4];
    const float* W_k     = (const float*)d_in[5];
    const float* w_v     = (const float*)d_in[6];
    float* out = (float*)d_out;

    // ws layout (~17.5 MB of 256 MiB):
    float*  kp  = (float*)d_ws;                          // 8 MB
    float*  qp  = kp + (size_t)BB * NK * HD;             // 1 MB
    float*  pO  = qp + (size_t)BB * NQ * HD;             // 8 MB
    float*  pM  = pO + (size_t)BB * 8 * 8 * 8 * 256;     // 32 KB
    float*  pL  = pM + (size_t)BB * 8 * 8 * 8;           // 32 KB
    ushort* wqh = (ushort*)(pL + (size_t)BB * 8 * 8 * 8);
    ushort* wql = wqh + 65536;
    ushort* wkh = wql + 65536;
    ushort* wkl = wkh + 65536;

    const float SC = 2.885390081777927f;                 // 2/ln(2)

    wconv<<<dim3(128), 256, 0, stream>>>(W_q, W_k, wqh, wql, wkh, wkl);
    proj_fused<<<dim3(144, 4), 256, 0, stream>>>(queries, keys,
                                                 wqh, wql, wkh, wkl,
                                                 qp, kp, SC);
    score_pv_seg2<<<dim3(128, 8), 256, 0, stream>>>(qp, kp, values, vlens, w_v,
                                                    pO, pM, pL);
    combine_seg2<<<dim3(BB * NQ), 256, 0, stream>>>(pO, pM, pL, vlens, out);
}

// Round 2
// 111.502 us; speedup vs baseline: 1.0292x; 1.0292x over previous
//
#include <hip/hip_runtime.h>
#include <hip/hip_bf16.h>

#define BB 16
#define NQ 64
#define NK 512
#define HD 256   // H = QS = KS = VD = 256

typedef __attribute__((ext_vector_type(8))) short short8;
typedef __attribute__((ext_vector_type(4))) float f32x4;

__device__ __forceinline__ ushort bf16_rne(float v) {
    unsigned u = __float_as_uint(v);
    return (ushort)((u + 0x7FFFu + ((u >> 16) & 1u)) >> 16);
}
__device__ __forceinline__ float bf16_to_f(ushort h) {
    return __uint_as_float(((unsigned)h) << 16);
}

// ---------------------------------------------------------------------------
// W-only conversion (tiny): W fp32 [k][n] -> hi/lo bf16 TRANSPOSED [n][k].
// 128 blocks.  Scattered L2 reads, coalesced ushort4 writes.
// ---------------------------------------------------------------------------
__global__ __launch_bounds__(256) void wconv(
    const float* __restrict__ wq, const float* __restrict__ wk,
    ushort* __restrict__ wqh, ushort* __restrict__ wql,
    ushort* __restrict__ wkh, ushort* __restrict__ wkl)
{
    int widx = blockIdx.x * 256 + threadIdx.x;     // 0..32767
    const float* W; ushort *wh, *wl;
    if (widx < 16384) { W = wq; wh = wqh; wl = wql; }
    else { W = wk; wh = wkh; wl = wkl; widx -= 16384; }
    int n  = widx >> 6;
    int k4 = (widx & 63) * 4;
    ushort hh[4], ll[4];
    #pragma unroll
    for (int c = 0; c < 4; ++c) {
        float v = W[(k4 + c) * 256 + n];
        hh[c] = bf16_rne(v);
        ll[c] = bf16_rne(v - bf16_to_f(hh[c]));
    }
    *(ushort4*)&wh[n * 256 + k4] = make_ushort4(hh[0], hh[1], hh[2], hh[3]);
    *(ushort4*)&wl[n * 256 + k4] = make_ushort4(ll[0], ll[1], ll[2], ll[3]);
}

// ---------------------------------------------------------------------------
// Projection GEMM with FUSED A-conversion: A fp32 -> hi/lo bf16 in registers
// -> XOR-swizzled LDS; W^T pre-converted (wconv).  C = AhWh + AlWh + AhWl,
// epilogue: exp2(acc*scale)  (score kernel consumes e^{2q}, e^{2k} directly).
// Tile 64x64, BK=64, 576 blocks (144 x 4), 4 waves.
// ---------------------------------------------------------------------------
__global__ __launch_bounds__(256, 2) void proj_fused(
    const float* __restrict__ queries, const float* __restrict__ keys,
    const ushort* __restrict__ wqh, const ushort* __restrict__ wql,
    const ushort* __restrict__ wkh, const ushort* __restrict__ wkl,
    float* __restrict__ qp, float* __restrict__ kp, float scale)
{
    __shared__ ushort AsH[64 * 64], AsL[64 * 64];
    __shared__ ushort BsH[64 * 64], BsL[64 * 64];

    const float* A; const ushort *Bh, *Bl; float* C; int rows0;
    const int bx = blockIdx.x;
    if (bx < 16) { A = queries; Bh = wqh; Bl = wql; C = qp; rows0 = bx * 64; }
    else         { A = keys;    Bh = wkh; Bl = wkl; C = kp; rows0 = (bx - 16) * 64; }
    const int cols0 = blockIdx.y * 64;

    const int t = threadIdx.x, lane = t & 63, wave = t >> 6;
    const int quad = lane >> 4, l15 = lane & 15;
    const int sr  = t >> 2;          // staging row / n: 0..63
    const int sc2 = (t & 3) * 2;     // chunk pair base: 0,2,4,6

    f32x4 acc[4];
    #pragma unroll
    for (int j = 0; j < 4; ++j) acc[j] = (f32x4){0.f, 0.f, 0.f, 0.f};

    for (int k0 = 0; k0 < 256; k0 += 64) {
        // global loads: A fp32 (16 elems), W^T bf16 hi/lo (2 chunks each)
        const float* arow = &A[(size_t)(rows0 + sr) * 256 + k0 + sc2 * 8];
        float4 a0 = *(const float4*)&arow[0];
        float4 a1 = *(const float4*)&arow[4];
        float4 a2 = *(const float4*)&arow[8];
        float4 a3 = *(const float4*)&arow[12];
        const ushort* bhp = &Bh[(size_t)(cols0 + sr) * 256 + k0 + sc2 * 8];
        const ushort* blp = &Bl[(size_t)(cols0 + sr) * 256 + k0 + sc2 * 8];
        short8 b0h = *(const short8*)&bhp[0];
        short8 b1h = *(const short8*)&bhp[8];
        short8 b0l = *(const short8*)&blp[0];
        short8 b1l = *(const short8*)&blp[8];

        __syncthreads();   // previous tile's compute done

        // convert A to hi/lo bf16, pack
        float av[16] = {a0.x, a0.y, a0.z, a0.w, a1.x, a1.y, a1.z, a1.w,
                        a2.x, a2.y, a2.z, a2.w, a3.x, a3.y, a3.z, a3.w};
        short8 ah0, ah1, al0, al1;
        #pragma unroll
        for (int e = 0; e < 8; ++e) {
            ushort h0 = bf16_rne(av[e]);
            ushort h1 = bf16_rne(av[8 + e]);
            ah0[e] = (short)h0;
            ah1[e] = (short)h1;
            al0[e] = (short)bf16_rne(av[e] - bf16_to_f(h0));
            al1[e] = (short)bf16_rne(av[8 + e] - bf16_to_f(h1));
        }
        // XOR-swizzled LDS stores (chunk slot = c ^ (row&7))
        {
            int s0 = sr * 8 + ((sc2 + 0) ^ (sr & 7));
            int s1 = sr * 8 + ((sc2 + 1) ^ (sr & 7));
            *(short8*)&AsH[s0 * 8] = ah0;
            *(short8*)&AsH[s1 * 8] = ah1;
            *(short8*)&AsL[s0 * 8] = al0;
            *(short8*)&AsL[s1 * 8] = al1;
            *(short8*)&BsH[s0 * 8] = b0h;
            *(short8*)&BsH[s1 * 8] = b1h;
            *(short8*)&BsL[s0 * 8] = b0l;
            *(short8*)&BsL[s1 * 8] = b1l;
        }
        __syncthreads();

        #pragma unroll
        for (int ks = 0; ks < 2; ++ks) {
            const int c = ks * 4 + quad;
            short8 aH, aL, bH[4], bL[4];
            {
                int r = wave * 16 + l15;
                int slot = r * 8 + (c ^ (r & 7));
                aH = *(const short8*)&AsH[slot * 8];
                aL = *(const short8*)&AsL[slot * 8];
            }
            #pragma unroll
            for (int ns = 0; ns < 4; ++ns) {
                int n = ns * 16 + l15;
                int slot = n * 8 + (c ^ (n & 7));
                bH[ns] = *(const short8*)&BsH[slot * 8];
                bL[ns] = *(const short8*)&BsL[slot * 8];
            }
            #pragma unroll
            for (int ns = 0; ns < 4; ++ns)
                acc[ns] = __builtin_amdgcn_mfma_f32_16x16x32_bf16(aH, bH[ns], acc[ns], 0, 0, 0);
            #pragma unroll
            for (int ns = 0; ns < 4; ++ns)
                acc[ns] = __builtin_amdgcn_mfma_f32_16x16x32_bf16(aL, bH[ns], acc[ns], 0, 0, 0);
            #pragma unroll
            for (int ns = 0; ns < 4; ++ns)
                acc[ns] = __builtin_amdgcn_mfma_f32_16x16x32_bf16(aH, bL[ns], acc[ns], 0, 0, 0);
        }
    }

    // epilogue: C/D col=lane&15, row=quad*4+reg.  Store exp2(x*scale).
    const int rbase = rows0 + wave * 16 + quad * 4;
    #pragma unroll
    for (int ns = 0; ns < 4; ++ns) {
        int col = cols0 + ns * 16 + l15;
        #pragma unroll
        for (int r = 0; r < 4; ++r)
            C[(size_t)(rbase + r) * 256 + col] =
                __builtin_amdgcn_exp2f(acc[ns][r] * scale);
    }
}

// ---------------------------------------------------------------------------
// Segment flash partial, qtile=8, 8 WAVES (512 thr): wave = (kq, hh) =
// key-quarter x h-half.  Doubles waves per alive block (latency hiding) and
// halves each wave's serial chain vs the 4-wave version (which ran at
// VALUBusy 15% / occupancy 14% -- pure latency-bound).
// ek prefetched fully into registers (8 float4) before the staging barrier.
// Score: s = sum_h w/(1+EQ*EK) via 4-way grouped rcp; halves combined via
// sP LDS buffer.  PV: wave handles 16 keys x 4 q-rows; part[4][8][260]
// cross-reduced by all 512 threads in one pass.
// ---------------------------------------------------------------------------
__global__ __launch_bounds__(512, 4) void score_pv_seg3(
    const float* __restrict__ qp,      // [B*NQ, H]  EQ = exp2(q * 2/ln2)
    const float* __restrict__ kp,      // [B*NK, H]  EK = exp2(k * 2/ln2)
    const float* __restrict__ values,  // [B, NK, VD]
    const int*   __restrict__ vlens,   // [B]
    const float* __restrict__ w_v,     // [H]
    float* __restrict__ pO,            // [B][8qt][8seg][8q][256]
    float* __restrict__ pM,            // [B][8qt][8seg][8q]
    float* __restrict__ pL)            // [B][8qt][8seg][8q]
{
    __shared__ float eq[8][260];
    __shared__ float wv[HD];
    __shared__ float Ps[8][66];
    __shared__ float sP[8][66];
    __shared__ float part[4][8][260];

    const int b   = blockIdx.x & 15;
    const int qt  = blockIdx.x >> 4;    // 0..7
    const int seg = blockIdx.y;         // 0..7
    const int vl  = vlens[b];
    if (seg * 64 >= vl) return;

    const int t = threadIdx.x, lane = t & 63, wave = t >> 6;  // wave 0..7
    const int kq = wave & 3;            // key quarter
    const int hh = wave >> 2;           // h half
    const int key = kq * 16 + (lane >> 2);   // 0..63
    const int ch  = lane & 3;
    const int kg  = seg * 64 + key;

    // ---- issue all 8 ek loads up-front (latency overlaps eq staging) ----
    const float* krow = kp + ((size_t)b * NK + kg) * HD + hh * 128 + ch * 4;
    float4 ek[8];
    #pragma unroll
    for (int j = 0; j < 8; ++j) ek[j] = *(const float4*)&krow[j * 16];

    // ---- stage EQ (8 rows x 256) and w: one float4 per thread ----
    const float* qsrc = qp + ((size_t)b * NQ + qt * 8) * HD;
    {
        int row = t >> 6, c4 = (t & 63) * 4;
        *(float4*)&eq[row][c4] = *(const float4*)&qsrc[(size_t)row * HD + c4];
    }
    if (t < 64) *(float4*)&wv[t * 4] = *(const float4*)&w_v[t * 4];
    __syncthreads();

    // Wsum
    float Wsum;
    {
        float ws = wv[lane] + wv[lane + 64] + wv[lane + 128] + wv[lane + 192];
        #pragma unroll
        for (int off = 32; off; off >>= 1) ws += __shfl_xor(ws, off);
        Wsum = ws;
    }

    // ---- scores over this wave's h-half ----
    float s[8] = {0.f, 0.f, 0.f, 0.f, 0.f, 0.f, 0.f, 0.f};
    #pragma unroll
    for (int j = 0; j < 8; ++j) {
        const int h = hh * 128 + j * 16 + ch * 4;
        float4 e4 = ek[j];
        float4 w4 = *(const float4*)&wv[h];
        #pragma unroll
        for (int qi = 0; qi < 8; ++qi) {
            float4 q4 = *(const float4*)&eq[qi][h];   // LDS broadcast (EQ)
            float p0 = fmaf(q4.x, e4.x, 1.f);
            float p1 = fmaf(q4.y, e4.y, 1.f);
            float p2 = fmaf(q4.z, e4.z, 1.f);
            float p3 = fmaf(q4.w, e4.w, 1.f);
            float d01 = p0 * p1;
            float d23 = p2 * p3;
            float n01 = fmaf(w4.x, p1, w4.y * p0);
            float n23 = fmaf(w4.z, p3, w4.w * p2);
            float num = fmaf(d01, n23, d23 * n01);
            float r   = __builtin_amdgcn_rcpf(d01 * d23);
            s[qi] = fmaf(num, r, s[qi]);
        }
    }
    #pragma unroll
    for (int qi = 0; qi < 8; ++qi) {
        s[qi] += __shfl_xor(s[qi], 1);
        s[qi] += __shfl_xor(s[qi], 2);
    }
    if (hh == 1 && ch == 0) {
        #pragma unroll
        for (int qi = 0; qi < 8; ++qi) sP[qi][key] = s[qi];
    }
    __syncthreads();
    if (hh == 0 && ch == 0) {
        const bool masked = (kg >= vl);
        #pragma unroll
        for (int qi = 0; qi < 8; ++qi)
            Ps[qi][key] = masked ? -1e6f
                                 : fmaf(-2.f, s[qi] + sP[qi][key], Wsum);
    }
    __syncthreads();

    // ---- per-segment softmax: wave w handles q row w ----
    const float L2E = 1.4426950408889634f;
    {
        const int row = wave;
        float sv = Ps[row][lane];
        float m = sv;
        #pragma unroll
        for (int off = 32; off; off >>= 1) m = fmaxf(m, __shfl_xor(m, off));
        float e = __builtin_amdgcn_exp2f((sv - m) * L2E);
        float l = e;
        #pragma unroll
        for (int off = 32; off; off >>= 1) l += __shfl_xor(l, off);
        Ps[row][lane] = e;
        if (lane == 0) {
            size_t mi = (((size_t)(b * 8 + qt) * 8 + seg)) * 8 + row;
            pM[mi] = m;
            pL[mi] = l;
        }
    }
    __syncthreads();

    // ---- PV: wave (kq,hh) -> 16 keys x 4 q-rows; lane owns vd = lane*4 ----
    f32x4 acc[4];
    #pragma unroll
    for (int r = 0; r < 4; ++r) acc[r] = (f32x4){0.f, 0.f, 0.f, 0.f};
    const float* vbase = values + ((size_t)b * NK + seg * 64 + kq * 16) * HD;
    #pragma unroll
    for (int i = 0; i < 16; ++i) {
        float4 v = *(const float4*)&vbase[(size_t)i * HD + lane * 4];
        #pragma unroll
        for (int r = 0; r < 4; ++r) {
            float p = Ps[hh * 4 + r][kq * 16 + i];    // LDS broadcast
            acc[r][0] = fmaf(p, v.x, acc[r][0]);
            acc[r][1] = fmaf(p, v.y, acc[r][1]);
            acc[r][2] = fmaf(p, v.z, acc[r][2]);
            acc[r][3] = fmaf(p, v.w, acc[r][3]);
        }
    }
    #pragma unroll
    for (int r = 0; r < 4; ++r)
        *(f32x4*)&part[kq][hh * 4 + r][lane * 4] = acc[r];
    __syncthreads();

    // ---- cross-wave reduce + store partials (512 thr, one float4 each) ----
    const size_t ob = (((size_t)(b * 8 + qt) * 8 + seg)) * 8 * 256;
    {
        int qi = t >> 6, c4 = (t & 63) * 4;
        float4 p0 = *(const float4*)&part[0][qi][c4];
        float4 p1 = *(const float4*)&part[1][qi][c4];
        float4 p2 = *(const float4*)&part[2][qi][c4];
        float4 p3 = *(const float4*)&part[3][qi][c4];
        float4 o;
        o.x = (p0.x + p1.x) + (p2.x + p3.x);
        o.y = (p0.y + p1.y) + (p2.y + p3.y);
        o.z = (p0.z + p1.z) + (p2.z + p3.z);
        o.w = (p0.w + p1.w) + (p2.w + p3.w);
        *(float4*)&pO[ob + (size_t)qi * 256 + c4] = o;
    }
}

// ---------------------------------------------------------------------------
// Combine: block per (b,q), 256 threads (one vd element each).
// O = sum_i e2(m_i-m)*O_i / sum_i e2(m_i-m)*l_i, i < nc (<=8 segs).
// ---------------------------------------------------------------------------
__global__ __launch_bounds__(256) void combine_seg2(
    const float* __restrict__ pO, const float* __restrict__ pM,
    const float* __restrict__ pL, const int* __restrict__ vlens,
    float* __restrict__ out)
{
    const int b  = blockIdx.x >> 6;
    const int q  = blockIdx.x & 63;
    const int t  = threadIdx.x;
    const int vl = vlens[b];
    const int nc = (vl + 63) >> 6;
    const int qt = q >> 3, qi = q & 7;
    const float L2E = 1.4426950408889634f;

    const size_t base = (size_t)(b * 8 + qt) * 8;   // + seg, then *8 + qi

    float mi[8], li[8];
    float m = -3e38f;
    #pragma unroll
    for (int i = 0; i < 8; ++i) {
        if (i < nc) {
            mi[i] = pM[(base + i) * 8 + qi];
            li[i] = pL[(base + i) * 8 + qi];
            m = fmaxf(m, mi[i]);
        }
    }
    float L = 0.f, wi[8];
    #pragma unroll
    for (int i = 0; i < 8; ++i) {
        if (i < nc) {
            wi[i] = __builtin_amdgcn_exp2f((mi[i] - m) * L2E);
            L = fmaf(li[i], wi[i], L);
        }
    }
    float acc = 0.f;
    #pragma unroll
    for (int i = 0; i < 8; ++i) {
        if (i < nc) acc = fmaf(wi[i], pO[((base + i) * 8 + qi) * 256 + t], acc);
    }
    out[((size_t)(b * 64 + q)) * 256 + t] = acc * __builtin_amdgcn_rcpf(L);
}

extern "C" void kernel_launch(void* const* d_in, const int* in_sizes, int n_in,
                              void* d_out, int out_size, void* d_ws, size_t ws_size,
                              hipStream_t stream) {
    const float* queries = (const float*)d_in[0];
    const float* keys    = (const float*)d_in[1];
    const float* values  = (const float*)d_in[2];
    const int*   vlens   = (const int*)d_in[3];
    const float* W_q     = (const float*)d_in[4];
    const float* W_k     = (const float*)d_in[5];
    const float* w_v     = (const float*)d_in[6];
    float* out = (float*)d_out;

    // ws layout (~17.5 MB of 256 MiB):
    float*  kp  = (float*)d_ws;                          // 8 MB
    float*  qp  = kp + (size_t)BB * NK * HD;             // 1 MB
    float*  pO  = qp + (size_t)BB * NQ * HD;             // 8 MB
    float*  pM  = pO + (size_t)BB * 8 * 8 * 8 * 256;     // 32 KB
    float*  pL  = pM + (size_t)BB * 8 * 8 * 8;           // 32 KB
    ushort* wqh = (ushort*)(pL + (size_t)BB * 8 * 8 * 8);
    ushort* wql = wqh + 65536;
    ushort* wkh = wql + 65536;
    ushort* wkl = wkh + 65536;

    const float SC = 2.885390081777927f;                 // 2/ln(2)

    wconv<<<dim3(128), 256, 0, stream>>>(W_q, W_k, wqh, wql, wkh, wkl);
    proj_fused<<<dim3(144, 4), 256, 0, stream>>>(queries, keys,
                                                 wqh, wql, wkh, wkl,
                                                 qp, kp, SC);
    score_pv_seg3<<<dim3(128, 8), 512, 0, stream>>>(qp, kp, values, vlens, w_v,
                                                    pO, pM, pL);
    combine_seg2<<<dim3(BB * NQ), 256, 0, stream>>>(pO, pM, pL, vlens, out);
}